// Round 2
// baseline (2987.115 us; speedup 1.0000x reference)
//
#include <hip/hip_runtime.h>
#include <cstdint>

#define D 128
#define P 8
#define L 3
#define ROWS 32

// row_ptr[r] = lower_bound(edge_row, r); edge_row is sorted.
__global__ void build_row_ptr(const int* __restrict__ er, int* __restrict__ rp, int n, int e) {
    int r = blockIdx.x * blockDim.x + threadIdx.x;
    if (r > n) return;
    int lo = 0, hi = e;
    while (lo < hi) {
        int mid = (lo + hi) >> 1;
        if (er[mid] < r) lo = mid + 1; else hi = mid;
    }
    rp[r] = lo;
}

// wwT[l][i][o] = sum_p sp[l][o][i][p] * softmax(lw[l])[p]   (transposed store)
__global__ void build_ww(const float* __restrict__ sp, const float* __restrict__ lw,
                         float* __restrict__ wwT) {
    int idx = blockIdx.x * blockDim.x + threadIdx.x;
    if (idx >= L * D * D) return;
    int l = idx / (D * D);
    int rem = idx - l * D * D;
    int o = rem / D;
    int i = rem - o * D;
    float wv[P];
    float m = -1e30f;
#pragma unroll
    for (int p = 0; p < P; p++) { wv[p] = lw[l * P + p]; m = fmaxf(m, wv[p]); }
    float s = 0.f;
#pragma unroll
    for (int p = 0; p < P; p++) { wv[p] = __expf(wv[p] - m); s += wv[p]; }
    float inv = 1.0f / s;
    const float* spp = sp + ((size_t)(l * D + o) * D + i) * P;
    float acc = 0.f;
#pragma unroll
    for (int p = 0; p < P; p++) acc += spp[p] * wv[p];
    wwT[(l * D + i) * D + o] = acc * inv;
}

// Fused: ax = SpMM(h_in) for 32 rows -> LDS; h_out = ax @ wwT (opt ReLU).
template<bool RELU>
__global__ __launch_bounds__(256, 2)
void layer_kernel(const float* __restrict__ h_in, const int* __restrict__ rp,
                  const int* __restrict__ col, const float* __restrict__ vals,
                  const float* __restrict__ wwT_l, float* __restrict__ h_out, int n) {
    __shared__ float s_ww[D * D];     // 64 KB, wwT[i][o]
    __shared__ float s_ax[ROWS][D];   // 16 KB
    const int tid = threadIdx.x;

    // Stage wwT into LDS (float4, coalesced). Issued first: long-latency, no deps.
    for (int k = tid * 4; k < D * D; k += 256 * 4) {
        *(float4*)&s_ww[k] = *(const float4*)&wwT_l[k];
    }

    // Phase 1: SpMM. 128 threads per row (d = feature), wave-uniform edge loop.
    const int row0 = blockIdx.x * ROWS;
    const int d = tid & (D - 1);
    for (int rr = (tid >> 7); rr < ROWS; rr += 2) {
        int r = row0 + rr;
        float acc = 0.f;
        if (r < n) {
            int e0 = rp[r], e1 = rp[r + 1];
            for (int e = e0; e < e1; e++) {
                acc += vals[e] * h_in[col[e] * D + d];
            }
        }
        s_ax[rr][d] = acc;
    }
    __syncthreads();

    // Phase 2: 32x128 GEMM, 4 rows x 4 cols per thread, float4 LDS reads.
    float acc[4][4] = {};
    const int oc = (tid & 31) * 4;         // output column base
    const int rc = (tid >> 5) * 4;         // row base within tile
    for (int i = 0; i < D; i += 4) {
        float4 av[4];
        av[0] = *(const float4*)&s_ax[rc + 0][i];
        av[1] = *(const float4*)&s_ax[rc + 1][i];
        av[2] = *(const float4*)&s_ax[rc + 2][i];
        av[3] = *(const float4*)&s_ax[rc + 3][i];
        const float* ap = reinterpret_cast<const float*>(av);
#pragma unroll
        for (int ii = 0; ii < 4; ii++) {
            float4 w = *(const float4*)&s_ww[(i + ii) * D + oc];
#pragma unroll
            for (int r = 0; r < 4; r++) {
                float a_ = ap[r * 4 + ii];
                acc[r][0] += a_ * w.x;
                acc[r][1] += a_ * w.y;
                acc[r][2] += a_ * w.z;
                acc[r][3] += a_ * w.w;
            }
        }
    }

#pragma unroll
    for (int r = 0; r < 4; r++) {
        int row = row0 + rc + r;
        if (row < n) {
            float4 v;
            v.x = RELU ? fmaxf(acc[r][0], 0.f) : acc[r][0];
            v.y = RELU ? fmaxf(acc[r][1], 0.f) : acc[r][1];
            v.z = RELU ? fmaxf(acc[r][2], 0.f) : acc[r][2];
            v.w = RELU ? fmaxf(acc[r][3], 0.f) : acc[r][3];
            *(float4*)&h_out[row * D + oc] = v;
        }
    }
}

extern "C" void kernel_launch(void* const* d_in, const int* in_sizes, int n_in,
                              void* d_out, int out_size, void* d_ws, size_t ws_size,
                              hipStream_t stream) {
    const int*   edge_row  = (const int*)d_in[0];
    const int*   edge_col  = (const int*)d_in[1];
    const float* edge_vals = (const float*)d_in[2];
    const float* x         = (const float*)d_in[3];
    const float* sp        = (const float*)d_in[4];
    const float* lw        = (const float*)d_in[5];
    float* out = (float*)d_out;

    const int E_ = in_sizes[0];
    const int N_ = in_sizes[3] / D;

    // Workspace layout: row_ptr | wwT (L*D*D) | hbuf (N*D)
    char* ws = (char*)d_ws;
    int* row_ptr = (int*)ws;
    size_t off = (((size_t)(N_ + 1) * sizeof(int)) + 255) & ~(size_t)255;
    float* wwT = (float*)(ws + off);
    off += (size_t)L * D * D * sizeof(float);
    float* hbuf = (float*)(ws + off);

    build_row_ptr<<<(N_ + 1 + 255) / 256, 256, 0, stream>>>(edge_row, row_ptr, N_, E_);
    build_ww<<<(L * D * D + 255) / 256, 256, 0, stream>>>(sp, lw, wwT);

    const int nblk = (N_ + ROWS - 1) / ROWS;
    // layer 0: x -> d_out (relu)
    layer_kernel<true ><<<nblk, 256, 0, stream>>>(x,    row_ptr, edge_col, edge_vals, wwT,             out,  N_);
    // layer 1: d_out -> hbuf (relu)
    layer_kernel<true ><<<nblk, 256, 0, stream>>>(out,  row_ptr, edge_col, edge_vals, wwT + D * D,     hbuf, N_);
    // layer 2: hbuf -> d_out (no relu)
    layer_kernel<false><<<nblk, 256, 0, stream>>>(hbuf, row_ptr, edge_col, edge_vals, wwT + 2 * D * D, out,  N_);
}

// Round 3
// 694.678 us; speedup vs baseline: 4.3000x; 4.3000x over previous
//
#include <hip/hip_runtime.h>
#include <cstdint>

#define D 128
#define P 8
#define L 3
#define ROWS 32

// row_ptr[r] = lower_bound(edge_row, r); edge_row is sorted.
__global__ void build_row_ptr(const int* __restrict__ er, int* __restrict__ rp, int n, int e) {
    int r = blockIdx.x * blockDim.x + threadIdx.x;
    if (r > n) return;
    int lo = 0, hi = e;
    while (lo < hi) {
        int mid = (lo + hi) >> 1;
        if (er[mid] < r) lo = mid + 1; else hi = mid;
    }
    rp[r] = lo;
}

// wwT[l][i][o] = sum_p sp[l][o][i][p] * softmax(lw[l])[p]   (transposed store)
__global__ void build_ww(const float* __restrict__ sp, const float* __restrict__ lw,
                         float* __restrict__ wwT) {
    int idx = blockIdx.x * blockDim.x + threadIdx.x;
    if (idx >= L * D * D) return;
    int l = idx / (D * D);
    int rem = idx - l * D * D;
    int o = rem / D;
    int i = rem - o * D;
    float wv[P];
    float m = -1e30f;
#pragma unroll
    for (int p = 0; p < P; p++) { wv[p] = lw[l * P + p]; m = fmaxf(m, wv[p]); }
    float s = 0.f;
#pragma unroll
    for (int p = 0; p < P; p++) { wv[p] = __expf(wv[p] - m); s += wv[p]; }
    float inv = 1.0f / s;
    const float* spp = sp + ((size_t)(l * D + o) * D + i) * P;
    float acc = 0.f;
#pragma unroll
    for (int p = 0; p < P; p++) acc += spp[p] * wv[p];
    wwT[(l * D + i) * D + o] = acc * inv;
}

// Fused: ax = SpMM(h_in) for 32 rows -> LDS; h_out = ax @ wwT (opt ReLU).
// Phase 1: 8 groups of 32 threads; each group owns a row, float4 gathers,
// 4 edges batched per step for memory-level parallelism.
template<bool RELU>
__global__ __launch_bounds__(256, 2)
void layer_kernel(const float* __restrict__ h_in, const int* __restrict__ rp,
                  const int* __restrict__ col, const float* __restrict__ vals,
                  const float* __restrict__ wwT_l, float* __restrict__ h_out, int n) {
    __shared__ float s_ww[D * D];     // 64 KB, wwT[i][o]
    __shared__ float s_ax[ROWS][D];   // 16 KB
    const int tid = threadIdx.x;

    // Stage wwT into LDS (float4, coalesced). Issued first: long-latency, no deps.
    for (int k = tid * 4; k < D * D; k += 256 * 4) {
        *(float4*)&s_ww[k] = *(const float4*)&wwT_l[k];
    }

    // Phase 1: SpMM. group g (32 threads) handles rows g, g+8, g+16, g+24.
    const int row0 = blockIdx.x * ROWS;
    const int g  = tid >> 5;          // 0..7
    const int c4 = (tid & 31) * 4;    // feature base, float4 per lane
    for (int rr = g; rr < ROWS; rr += 8) {
        int r = row0 + rr;
        float4 acc = {0.f, 0.f, 0.f, 0.f};
        if (r < n) {
            int e = rp[r], e1 = rp[r + 1];
            // batched: 4 independent gathers in flight per step
            for (; e + 4 <= e1; e += 4) {
                int   c0 = col[e],     c1 = col[e + 1], c2 = col[e + 2], c3 = col[e + 3];
                float v0 = vals[e],    v1 = vals[e + 1], v2 = vals[e + 2], v3 = vals[e + 3];
                float4 g0 = *(const float4*)&h_in[c0 * D + c4];
                float4 g1 = *(const float4*)&h_in[c1 * D + c4];
                float4 g2 = *(const float4*)&h_in[c2 * D + c4];
                float4 g3 = *(const float4*)&h_in[c3 * D + c4];
                acc.x += v0 * g0.x + v1 * g1.x + v2 * g2.x + v3 * g3.x;
                acc.y += v0 * g0.y + v1 * g1.y + v2 * g2.y + v3 * g3.y;
                acc.z += v0 * g0.z + v1 * g1.z + v2 * g2.z + v3 * g3.z;
                acc.w += v0 * g0.w + v1 * g1.w + v2 * g2.w + v3 * g3.w;
            }
            for (; e < e1; e++) {
                int   c = col[e];
                float v = vals[e];
                float4 gg = *(const float4*)&h_in[c * D + c4];
                acc.x += v * gg.x; acc.y += v * gg.y;
                acc.z += v * gg.z; acc.w += v * gg.w;
            }
        }
        *(float4*)&s_ax[rr][c4] = acc;
    }
    __syncthreads();

    // Phase 2: 32x128 GEMM, 4 rows x 4 cols per thread, float4 LDS reads.
    float acc[4][4] = {};
    const int oc = (tid & 31) * 4;         // output column base
    const int rc = (tid >> 5) * 4;         // row base within tile
    for (int i = 0; i < D; i += 4) {
        float4 av[4];
        av[0] = *(const float4*)&s_ax[rc + 0][i];
        av[1] = *(const float4*)&s_ax[rc + 1][i];
        av[2] = *(const float4*)&s_ax[rc + 2][i];
        av[3] = *(const float4*)&s_ax[rc + 3][i];
        const float* ap = reinterpret_cast<const float*>(av);
#pragma unroll
        for (int ii = 0; ii < 4; ii++) {
            float4 w = *(const float4*)&s_ww[(i + ii) * D + oc];
#pragma unroll
            for (int r = 0; r < 4; r++) {
                float a_ = ap[r * 4 + ii];
                acc[r][0] += a_ * w.x;
                acc[r][1] += a_ * w.y;
                acc[r][2] += a_ * w.z;
                acc[r][3] += a_ * w.w;
            }
        }
    }

#pragma unroll
    for (int r = 0; r < 4; r++) {
        int row = row0 + rc + r;
        if (row < n) {
            float4 v;
            v.x = RELU ? fmaxf(acc[r][0], 0.f) : acc[r][0];
            v.y = RELU ? fmaxf(acc[r][1], 0.f) : acc[r][1];
            v.z = RELU ? fmaxf(acc[r][2], 0.f) : acc[r][2];
            v.w = RELU ? fmaxf(acc[r][3], 0.f) : acc[r][3];
            *(float4*)&h_out[row * D + oc] = v;
        }
    }
}

extern "C" void kernel_launch(void* const* d_in, const int* in_sizes, int n_in,
                              void* d_out, int out_size, void* d_ws, size_t ws_size,
                              hipStream_t stream) {
    const int*   edge_row  = (const int*)d_in[0];
    const int*   edge_col  = (const int*)d_in[1];
    const float* edge_vals = (const float*)d_in[2];
    const float* x         = (const float*)d_in[3];
    const float* sp        = (const float*)d_in[4];
    const float* lw        = (const float*)d_in[5];
    float* out = (float*)d_out;

    const int E_ = in_sizes[0];
    const int N_ = in_sizes[3] / D;

    // Workspace layout: row_ptr | wwT (L*D*D) | hbuf (N*D)
    char* ws = (char*)d_ws;
    int* row_ptr = (int*)ws;
    size_t off = (((size_t)(N_ + 1) * sizeof(int)) + 255) & ~(size_t)255;
    float* wwT = (float*)(ws + off);
    off += (size_t)L * D * D * sizeof(float);
    float* hbuf = (float*)(ws + off);

    build_row_ptr<<<(N_ + 1 + 255) / 256, 256, 0, stream>>>(edge_row, row_ptr, N_, E_);
    build_ww<<<(L * D * D + 255) / 256, 256, 0, stream>>>(sp, lw, wwT);

    const int nblk = (N_ + ROWS - 1) / ROWS;
    // layer 0: x -> d_out (relu)
    layer_kernel<true ><<<nblk, 256, 0, stream>>>(x,    row_ptr, edge_col, edge_vals, wwT,             out,  N_);
    // layer 1: d_out -> hbuf (relu)
    layer_kernel<true ><<<nblk, 256, 0, stream>>>(out,  row_ptr, edge_col, edge_vals, wwT + D * D,     hbuf, N_);
    // layer 2: hbuf -> d_out (no relu)
    layer_kernel<false><<<nblk, 256, 0, stream>>>(hbuf, row_ptr, edge_col, edge_vals, wwT + 2 * D * D, out,  N_);
}

// Round 4
// 547.228 us; speedup vs baseline: 5.4586x; 1.2695x over previous
//
#include <hip/hip_runtime.h>
#include <cstdint>

#define D 128
#define P 8
#define L 3
#define ROWS 32

// row_ptr[r] = lower_bound(edge_row, r); edge_row is sorted.
__global__ void build_row_ptr(const int* __restrict__ er, int* __restrict__ rp, int n, int e) {
    int r = blockIdx.x * blockDim.x + threadIdx.x;
    if (r > n) return;
    int lo = 0, hi = e;
    while (lo < hi) {
        int mid = (lo + hi) >> 1;
        if (er[mid] < r) lo = mid + 1; else hi = mid;
    }
    rp[r] = lo;
}

// wwT[l][i][o] = sum_p sp[l][o][i][p] * softmax(lw[l])[p]   (transposed store)
__global__ void build_ww(const float* __restrict__ sp, const float* __restrict__ lw,
                         float* __restrict__ wwT) {
    int idx = blockIdx.x * blockDim.x + threadIdx.x;
    if (idx >= L * D * D) return;
    int l = idx / (D * D);
    int rem = idx - l * D * D;
    int o = rem / D;
    int i = rem - o * D;
    float wv[P];
    float m = -1e30f;
#pragma unroll
    for (int p = 0; p < P; p++) { wv[p] = lw[l * P + p]; m = fmaxf(m, wv[p]); }
    float s = 0.f;
#pragma unroll
    for (int p = 0; p < P; p++) { wv[p] = __expf(wv[p] - m); s += wv[p]; }
    float inv = 1.0f / s;
    const float* spp = sp + ((size_t)(l * D + o) * D + i) * P;
    float acc = 0.f;
#pragma unroll
    for (int p = 0; p < P; p++) acc += spp[p] * wv[p];
    wwT[(l * D + i) * D + o] = acc * inv;
}

// Fused: ax = SpMM(h_in) for 32 rows -> LDS; h_out = ax @ wwT (opt ReLU).
// LDS = s_ax only (16 KB): ww is read from global in phase 2 (L1/L2-resident,
// shared by all blocks). 4 blocks/CU -> 16 waves/CU for gather MLP.
template<bool RELU>
__global__ __launch_bounds__(256, 4)
void layer_kernel(const float* __restrict__ h_in, const int* __restrict__ rp,
                  const int* __restrict__ col, const float* __restrict__ vals,
                  const float* __restrict__ wwT_l, float* __restrict__ h_out, int n) {
    __shared__ float s_ax[ROWS][D];   // 16 KB
    const int tid = threadIdx.x;

    // Phase 1: SpMM. group g (32 threads) handles rows g, g+8, g+16, g+24.
    // 8 edges batched per step: 8 independent float4 gathers in flight/lane.
    const int row0 = blockIdx.x * ROWS;
    const int g  = tid >> 5;          // 0..7
    const int c4 = (tid & 31) * 4;    // feature base, float4 per lane
    for (int rr = g; rr < ROWS; rr += 8) {
        int r = row0 + rr;
        float4 acc = {0.f, 0.f, 0.f, 0.f};
        if (r < n) {
            int e = rp[r], e1 = rp[r + 1];
            for (; e + 8 <= e1; e += 8) {
                int   c[8]; float v[8]; float4 gg[8];
#pragma unroll
                for (int j = 0; j < 8; j++) { c[j] = col[e + j]; v[j] = vals[e + j]; }
#pragma unroll
                for (int j = 0; j < 8; j++) gg[j] = *(const float4*)&h_in[c[j] * D + c4];
#pragma unroll
                for (int j = 0; j < 8; j++) {
                    acc.x += v[j] * gg[j].x; acc.y += v[j] * gg[j].y;
                    acc.z += v[j] * gg[j].z; acc.w += v[j] * gg[j].w;
                }
            }
            for (; e + 4 <= e1; e += 4) {
                int   c[4]; float v[4]; float4 gg[4];
#pragma unroll
                for (int j = 0; j < 4; j++) { c[j] = col[e + j]; v[j] = vals[e + j]; }
#pragma unroll
                for (int j = 0; j < 4; j++) gg[j] = *(const float4*)&h_in[c[j] * D + c4];
#pragma unroll
                for (int j = 0; j < 4; j++) {
                    acc.x += v[j] * gg[j].x; acc.y += v[j] * gg[j].y;
                    acc.z += v[j] * gg[j].z; acc.w += v[j] * gg[j].w;
                }
            }
            for (; e < e1; e++) {
                int   cc = col[e];
                float vv = vals[e];
                float4 gg = *(const float4*)&h_in[cc * D + c4];
                acc.x += vv * gg.x; acc.y += vv * gg.y;
                acc.z += vv * gg.z; acc.w += vv * gg.w;
            }
        }
        *(float4*)&s_ax[rr][c4] = acc;
    }
    __syncthreads();

    // Phase 2: 32x128 GEMM, 4 rows x 4 cols per thread; A from LDS (broadcast),
    // W from global (L1/L2-hit: same lines touched by every block).
    float acc[4][4] = {};
    const int oc = (tid & 31) * 4;         // output column base
    const int rc = (tid >> 5) * 4;         // row base within tile
    for (int i = 0; i < D; i += 4) {
        float4 av[4];
        av[0] = *(const float4*)&s_ax[rc + 0][i];
        av[1] = *(const float4*)&s_ax[rc + 1][i];
        av[2] = *(const float4*)&s_ax[rc + 2][i];
        av[3] = *(const float4*)&s_ax[rc + 3][i];
        float4 w[4];
#pragma unroll
        for (int ii = 0; ii < 4; ii++) w[ii] = *(const float4*)&wwT_l[(i + ii) * D + oc];
        const float* ap = reinterpret_cast<const float*>(av);
#pragma unroll
        for (int ii = 0; ii < 4; ii++) {
#pragma unroll
            for (int r = 0; r < 4; r++) {
                float a_ = ap[r * 4 + ii];
                acc[r][0] += a_ * w[ii].x;
                acc[r][1] += a_ * w[ii].y;
                acc[r][2] += a_ * w[ii].z;
                acc[r][3] += a_ * w[ii].w;
            }
        }
    }

#pragma unroll
    for (int r = 0; r < 4; r++) {
        int row = row0 + rc + r;
        if (row < n) {
            float4 v;
            v.x = RELU ? fmaxf(acc[r][0], 0.f) : acc[r][0];
            v.y = RELU ? fmaxf(acc[r][1], 0.f) : acc[r][1];
            v.z = RELU ? fmaxf(acc[r][2], 0.f) : acc[r][2];
            v.w = RELU ? fmaxf(acc[r][3], 0.f) : acc[r][3];
            *(float4*)&h_out[row * D + oc] = v;
        }
    }
}

extern "C" void kernel_launch(void* const* d_in, const int* in_sizes, int n_in,
                              void* d_out, int out_size, void* d_ws, size_t ws_size,
                              hipStream_t stream) {
    const int*   edge_row  = (const int*)d_in[0];
    const int*   edge_col  = (const int*)d_in[1];
    const float* edge_vals = (const float*)d_in[2];
    const float* x         = (const float*)d_in[3];
    const float* sp        = (const float*)d_in[4];
    const float* lw        = (const float*)d_in[5];
    float* out = (float*)d_out;

    const int E_ = in_sizes[0];
    const int N_ = in_sizes[3] / D;

    // Workspace layout: row_ptr | wwT (L*D*D) | hbuf (N*D)
    char* ws = (char*)d_ws;
    int* row_ptr = (int*)ws;
    size_t off = (((size_t)(N_ + 1) * sizeof(int)) + 255) & ~(size_t)255;
    float* wwT = (float*)(ws + off);
    off += (size_t)L * D * D * sizeof(float);
    float* hbuf = (float*)(ws + off);

    build_row_ptr<<<(N_ + 1 + 255) / 256, 256, 0, stream>>>(edge_row, row_ptr, N_, E_);
    build_ww<<<(L * D * D + 255) / 256, 256, 0, stream>>>(sp, lw, wwT);

    const int nblk = (N_ + ROWS - 1) / ROWS;
    // layer 0: x -> d_out (relu)
    layer_kernel<true ><<<nblk, 256, 0, stream>>>(x,    row_ptr, edge_col, edge_vals, wwT,             out,  N_);
    // layer 1: d_out -> hbuf (relu)
    layer_kernel<true ><<<nblk, 256, 0, stream>>>(out,  row_ptr, edge_col, edge_vals, wwT + D * D,     hbuf, N_);
    // layer 2: hbuf -> d_out (no relu)
    layer_kernel<false><<<nblk, 256, 0, stream>>>(hbuf, row_ptr, edge_col, edge_vals, wwT + 2 * D * D, out,  N_);
}

// Round 5
// 427.461 us; speedup vs baseline: 6.9880x; 1.2802x over previous
//
#include <hip/hip_runtime.h>
#include <cstdint>

#define D 128
#define P 8
#define L 3
#define ROWS 32

// fp32 -> bf16 round-to-nearest-even
static __device__ __forceinline__ unsigned short f2bf(float f) {
    unsigned u = __float_as_uint(f);
    u += 0x7fffu + ((u >> 16) & 1u);
    return (unsigned short)(u >> 16);
}

// row_ptr[r] = lower_bound(edge_row, r); edge_row is sorted.
__global__ void build_row_ptr(const int* __restrict__ er, int* __restrict__ rp, int n, int e) {
    int r = blockIdx.x * blockDim.x + threadIdx.x;
    if (r > n) return;
    int lo = 0, hi = e;
    while (lo < hi) {
        int mid = (lo + hi) >> 1;
        if (er[mid] < r) lo = mid + 1; else hi = mid;
    }
    rp[r] = lo;
}

// wwT[l][i][o] = sum_p sp[l][o][i][p] * softmax(lw[l])[p]   (transposed store)
__global__ void build_ww(const float* __restrict__ sp, const float* __restrict__ lw,
                         float* __restrict__ wwT) {
    int idx = blockIdx.x * blockDim.x + threadIdx.x;
    if (idx >= L * D * D) return;
    int l = idx / (D * D);
    int rem = idx - l * D * D;
    int o = rem / D;
    int i = rem - o * D;
    float wv[P];
    float m = -1e30f;
#pragma unroll
    for (int p = 0; p < P; p++) { wv[p] = lw[l * P + p]; m = fmaxf(m, wv[p]); }
    float s = 0.f;
#pragma unroll
    for (int p = 0; p < P; p++) { wv[p] = __expf(wv[p] - m); s += wv[p]; }
    float inv = 1.0f / s;
    const float* spp = sp + ((size_t)(l * D + o) * D + i) * P;
    float acc = 0.f;
#pragma unroll
    for (int p = 0; p < P; p++) acc += spp[p] * wv[p];
    wwT[(l * D + i) * D + o] = acc * inv;
}

// fp32 x -> bf16 (RNE), float4 in / ushort4 out
__global__ void cast_bf16(const float* __restrict__ x, unsigned short* __restrict__ xb,
                          int total4) {
    int i = blockIdx.x * blockDim.x + threadIdx.x;
    if (i >= total4) return;
    float4 v = ((const float4*)x)[i];
    ushort4 o;
    o.x = f2bf(v.x); o.y = f2bf(v.y); o.z = f2bf(v.z); o.w = f2bf(v.w);
    ((ushort4*)xb)[i] = o;
}

// one bf16x8 gather FMA'd into 8 fp32 accumulators
static __device__ __forceinline__ void bf8_fma(float (&a)[8], uint4 g, float v) {
    a[0] += v * __uint_as_float(g.x << 16);
    a[1] += v * __uint_as_float(g.x & 0xffff0000u);
    a[2] += v * __uint_as_float(g.y << 16);
    a[3] += v * __uint_as_float(g.y & 0xffff0000u);
    a[4] += v * __uint_as_float(g.z << 16);
    a[5] += v * __uint_as_float(g.z & 0xffff0000u);
    a[6] += v * __uint_as_float(g.w << 16);
    a[7] += v * __uint_as_float(g.w & 0xffff0000u);
}

// Fused: ax = SpMM(h_in bf16) for 32 rows -> LDS(fp32); h_out = ax @ wwT (+ReLU).
// Phase 1: 16 lanes per row, ushort8 (16B) gathers, 8 edges batched.
template<bool OUT_BF16, bool RELU>
__global__ __launch_bounds__(256, 4)
void layer_kernel(const unsigned short* __restrict__ h_in, const int* __restrict__ rp,
                  const int* __restrict__ col, const float* __restrict__ vals,
                  const float* __restrict__ wwT_l, void* __restrict__ h_out, int n) {
    __shared__ float s_ax[ROWS][D];   // 16 KB
    const int tid = threadIdx.x;
    const int row0 = blockIdx.x * ROWS;

    // Phase 1: subgroup sg (16 lanes) handles rows sg, sg+16.
    const int sg = tid >> 4;          // 0..15
    const int c8 = (tid & 15) * 8;    // feature base, 8 bf16 per lane
    for (int rr = sg; rr < ROWS; rr += 16) {
        int r = row0 + rr;
        float a[8] = {0.f, 0.f, 0.f, 0.f, 0.f, 0.f, 0.f, 0.f};
        if (r < n) {
            int e = rp[r], e1 = rp[r + 1];
            for (; e + 8 <= e1; e += 8) {
                int c[8]; float v[8]; uint4 g8[8];
#pragma unroll
                for (int j = 0; j < 8; j++) { c[j] = col[e + j]; v[j] = vals[e + j]; }
#pragma unroll
                for (int j = 0; j < 8; j++) g8[j] = *(const uint4*)&h_in[c[j] * D + c8];
#pragma unroll
                for (int j = 0; j < 8; j++) bf8_fma(a, g8[j], v[j]);
            }
            for (; e + 4 <= e1; e += 4) {
                int c[4]; float v[4]; uint4 g4[4];
#pragma unroll
                for (int j = 0; j < 4; j++) { c[j] = col[e + j]; v[j] = vals[e + j]; }
#pragma unroll
                for (int j = 0; j < 4; j++) g4[j] = *(const uint4*)&h_in[c[j] * D + c8];
#pragma unroll
                for (int j = 0; j < 4; j++) bf8_fma(a, g4[j], v[j]);
            }
            for (; e < e1; e++) {
                uint4 g = *(const uint4*)&h_in[col[e] * D + c8];
                bf8_fma(a, g, vals[e]);
            }
        }
        *(float4*)&s_ax[rr][c8]     = make_float4(a[0], a[1], a[2], a[3]);
        *(float4*)&s_ax[rr][c8 + 4] = make_float4(a[4], a[5], a[6], a[7]);
    }
    __syncthreads();

    // Phase 2: 32x128 GEMM, 4 rows x 4 cols per thread; A from LDS,
    // W from global (L1/L2-hit: same 64 KB touched by every block).
    float acc[4][4] = {};
    const int oc = (tid & 31) * 4;         // output column base
    const int rc = (tid >> 5) * 4;         // row base within tile
    for (int i = 0; i < D; i += 4) {
        float4 av[4];
        av[0] = *(const float4*)&s_ax[rc + 0][i];
        av[1] = *(const float4*)&s_ax[rc + 1][i];
        av[2] = *(const float4*)&s_ax[rc + 2][i];
        av[3] = *(const float4*)&s_ax[rc + 3][i];
        float4 w[4];
#pragma unroll
        for (int ii = 0; ii < 4; ii++) w[ii] = *(const float4*)&wwT_l[(i + ii) * D + oc];
        const float* ap = reinterpret_cast<const float*>(av);
#pragma unroll
        for (int ii = 0; ii < 4; ii++) {
#pragma unroll
            for (int r = 0; r < 4; r++) {
                float a_ = ap[r * 4 + ii];
                acc[r][0] += a_ * w[ii].x;
                acc[r][1] += a_ * w[ii].y;
                acc[r][2] += a_ * w[ii].z;
                acc[r][3] += a_ * w[ii].w;
            }
        }
    }

#pragma unroll
    for (int r = 0; r < 4; r++) {
        int row = row0 + rc + r;
        if (row < n) {
            float vx = RELU ? fmaxf(acc[r][0], 0.f) : acc[r][0];
            float vy = RELU ? fmaxf(acc[r][1], 0.f) : acc[r][1];
            float vz = RELU ? fmaxf(acc[r][2], 0.f) : acc[r][2];
            float vw = RELU ? fmaxf(acc[r][3], 0.f) : acc[r][3];
            if constexpr (OUT_BF16) {
                unsigned short* ho = (unsigned short*)h_out;
                ushort4 o;
                o.x = f2bf(vx); o.y = f2bf(vy); o.z = f2bf(vz); o.w = f2bf(vw);
                *(ushort4*)&ho[row * D + oc] = o;
            } else {
                float* ho = (float*)h_out;
                *(float4*)&ho[row * D + oc] = make_float4(vx, vy, vz, vw);
            }
        }
    }
}

extern "C" void kernel_launch(void* const* d_in, const int* in_sizes, int n_in,
                              void* d_out, int out_size, void* d_ws, size_t ws_size,
                              hipStream_t stream) {
    const int*   edge_row  = (const int*)d_in[0];
    const int*   edge_col  = (const int*)d_in[1];
    const float* edge_vals = (const float*)d_in[2];
    const float* x         = (const float*)d_in[3];
    const float* sp        = (const float*)d_in[4];
    const float* lw        = (const float*)d_in[5];
    float* out = (float*)d_out;

    const int E_ = in_sizes[0];
    const int N_ = in_sizes[3] / D;

    // Workspace: row_ptr | wwT | xb (bf16, aliased by hb) | ha (bf16)
    char* ws = (char*)d_ws;
    int* row_ptr = (int*)ws;
    size_t off = (((size_t)(N_ + 1) * sizeof(int)) + 255) & ~(size_t)255;
    float* wwT = (float*)(ws + off);
    off += (size_t)L * D * D * sizeof(float);
    unsigned short* xb = (unsigned short*)(ws + off);   // also hb (x dead after layer 0)
    off += (size_t)N_ * D * sizeof(unsigned short);
    unsigned short* ha = (unsigned short*)(ws + off);

    build_row_ptr<<<(N_ + 1 + 255) / 256, 256, 0, stream>>>(edge_row, row_ptr, N_, E_);
    build_ww<<<(L * D * D + 255) / 256, 256, 0, stream>>>(sp, lw, wwT);
    cast_bf16<<<(N_ * D / 4 + 255) / 256, 256, 0, stream>>>(x, xb, N_ * D / 4);

    const int nblk = (N_ + ROWS - 1) / ROWS;
    // layer 0: xb -> ha (relu, bf16 out)
    layer_kernel<true,  true ><<<nblk, 256, 0, stream>>>(xb, row_ptr, edge_col, edge_vals,
                                                         wwT,             ha, N_);
    // layer 1: ha -> xb-region (relu, bf16 out)
    layer_kernel<true,  true ><<<nblk, 256, 0, stream>>>(ha, row_ptr, edge_col, edge_vals,
                                                         wwT + D * D,     xb, N_);
    // layer 2: xb-region -> d_out (no relu, fp32 out)
    layer_kernel<false, false><<<nblk, 256, 0, stream>>>(xb, row_ptr, edge_col, edge_vals,
                                                         wwT + 2 * D * D, out, N_);
}

// Round 7
// 368.655 us; speedup vs baseline: 8.1027x; 1.1595x over previous
//
#include <hip/hip_runtime.h>
#include <cstdint>

#define D 128
#define P 8
#define L 3

typedef __attribute__((ext_vector_type(8))) _Float16 f16x8;
typedef __attribute__((ext_vector_type(4))) _Float16 f16x4;
typedef __attribute__((ext_vector_type(4))) float    f32x4;

// row_ptr[r] = lower_bound(edge_row, r); edge_row is sorted.
__global__ void build_row_ptr(const int* __restrict__ er, int* __restrict__ rp, int n, int e) {
    int r = blockIdx.x * blockDim.x + threadIdx.x;
    if (r > n) return;
    int lo = 0, hi = e;
    while (lo < hi) {
        int mid = (lo + hi) >> 1;
        if (er[mid] < r) lo = mid + 1; else hi = mid;
    }
    rp[r] = lo;
}

// ww = softmax-contracted weights, stored fp16 in MFMA B-fragment layout:
// wwB[l][kt][o][k']  (i = kt*32 + k'), so a b-frag load is 16B contiguous.
__global__ void build_ww(const float* __restrict__ sp, const float* __restrict__ lw,
                         _Float16* __restrict__ wwB) {
    int idx = blockIdx.x * blockDim.x + threadIdx.x;
    if (idx >= L * D * D) return;
    int l = idx / (D * D);
    int rem = idx - l * D * D;
    int o = rem / D;
    int i = rem - o * D;
    float wv[P];
    float m = -1e30f;
#pragma unroll
    for (int p = 0; p < P; p++) { wv[p] = lw[l * P + p]; m = fmaxf(m, wv[p]); }
    float s = 0.f;
#pragma unroll
    for (int p = 0; p < P; p++) { wv[p] = __expf(wv[p] - m); s += wv[p]; }
    float inv = 1.0f / s;
    const float* spp = sp + ((size_t)(l * D + o) * D + i) * P;
    float acc = 0.f;
#pragma unroll
    for (int p = 0; p < P; p++) acc += spp[p] * wv[p];
    int kt = i >> 5, kp = i & 31;
    wwB[(((l * 4 + kt) * D + o) << 5) + kp] = (_Float16)(acc * inv);
}

// fp32 x -> fp16
__global__ void cast_f16(const float* __restrict__ x, _Float16* __restrict__ xh, int total4) {
    int i = blockIdx.x * blockDim.x + threadIdx.x;
    if (i >= total4) return;
    float4 v = ((const float4*)x)[i];
    f16x4 o;
    o.x = (_Float16)v.x; o.y = (_Float16)v.y; o.z = (_Float16)v.z; o.w = (_Float16)v.w;
    ((f16x4*)xh)[i] = o;
}

// Y = H * W  (in-place safe: block reads its 64 rows into LDS, then overwrites
// exactly those rows). MFMA 16x16x32 f16. W from global in b-frag layout
// (32 KB, L1-resident across blocks).
__global__ __launch_bounds__(256, 4)
void gemm_xw(const _Float16* __restrict__ h, const _Float16* __restrict__ wwB_l,
             _Float16* __restrict__ y, int n) {
    __shared__ _Float16 s_h[64][136];   // +8 pad
    const int tid = threadIdx.x;
    const int row0 = blockIdx.x * 64;
    {
        const int c8 = (tid & 15) * 8;
        for (int r = tid >> 4; r < 64; r += 16) {   // FIX: stage ALL 64 rows
            int row = row0 + r;
            f16x8 v = {};
            if (row < n) v = *(const f16x8*)&h[row * D + c8];
            *(f16x8*)&s_h[r][c8] = v;
        }
    }
    __syncthreads();

    const int w = tid >> 6, lane = tid & 63;
    const int quad = lane >> 4, l16 = lane & 15;
    f32x4 acc[8] = {};
    const int arow = w * 16 + l16;
#pragma unroll
    for (int kt = 0; kt < 4; kt++) {
        f16x8 af = *(const f16x8*)&s_h[arow][kt * 32 + quad * 8];
#pragma unroll
        for (int ct = 0; ct < 8; ct++) {
            f16x8 bf = *(const f16x8*)&wwB_l[((kt * D + ct * 16 + l16) << 5) + quad * 8];
            acc[ct] = __builtin_amdgcn_mfma_f32_16x16x32_f16(af, bf, acc[ct], 0, 0, 0);
        }
    }
    // C/D layout: col = lane&15, row = quad*4 + reg (m89-verified)
#pragma unroll
    for (int ct = 0; ct < 8; ct++) {
#pragma unroll
        for (int rg = 0; rg < 4; rg++) {
            int row = row0 + w * 16 + quad * 4 + rg;
            if (row < n) y[row * D + ct * 16 + l16] = (_Float16)acc[ct][rg];
        }
    }
}

// h' = act(A * Y): pure gather-accumulate. 16 lanes/row, uint4 (8 fp16)
// gathers, 8 edges batched for MLP. fp32 accumulate.
template<bool OUT_F16, bool RELU>
__global__ __launch_bounds__(256, 4)
void spmm(const _Float16* __restrict__ y, const int* __restrict__ rp,
          const int* __restrict__ col, const float* __restrict__ vals,
          void* __restrict__ h_out, int n) {
    const int tid = threadIdx.x;
    const int r = blockIdx.x * 16 + (tid >> 4);
    const int c8 = (tid & 15) * 8;
    if (r >= n) return;
    union U8 { uint4 u; _Float16 h[8]; };
    float a[8] = {0.f, 0.f, 0.f, 0.f, 0.f, 0.f, 0.f, 0.f};
    int e = rp[r], e1 = rp[r + 1];
    for (; e + 8 <= e1; e += 8) {
        int c[8]; float v[8]; U8 g[8];
#pragma unroll
        for (int j = 0; j < 8; j++) { c[j] = col[e + j]; v[j] = vals[e + j]; }
#pragma unroll
        for (int j = 0; j < 8; j++) g[j].u = *(const uint4*)&y[c[j] * D + c8];
#pragma unroll
        for (int j = 0; j < 8; j++)
#pragma unroll
            for (int k = 0; k < 8; k++) a[k] += v[j] * (float)g[j].h[k];
    }
    for (; e + 4 <= e1; e += 4) {
        int c[4]; float v[4]; U8 g[4];
#pragma unroll
        for (int j = 0; j < 4; j++) { c[j] = col[e + j]; v[j] = vals[e + j]; }
#pragma unroll
        for (int j = 0; j < 4; j++) g[j].u = *(const uint4*)&y[c[j] * D + c8];
#pragma unroll
        for (int j = 0; j < 4; j++)
#pragma unroll
            for (int k = 0; k < 8; k++) a[k] += v[j] * (float)g[j].h[k];
    }
    for (; e < e1; e++) {
        U8 g; g.u = *(const uint4*)&y[col[e] * D + c8];
        float v = vals[e];
#pragma unroll
        for (int k = 0; k < 8; k++) a[k] += v * (float)g.h[k];
    }
    if constexpr (OUT_F16) {
        _Float16* ho = (_Float16*)h_out;
        f16x8 o;
#pragma unroll
        for (int k = 0; k < 8; k++) {
            float t = RELU ? fmaxf(a[k], 0.f) : a[k];
            o[k] = (_Float16)t;
        }
        *(f16x8*)&ho[r * D + c8] = o;
    } else {
        float* ho = (float*)h_out;
        *(float4*)&ho[r * D + c8]     = make_float4(a[0], a[1], a[2], a[3]);
        *(float4*)&ho[r * D + c8 + 4] = make_float4(a[4], a[5], a[6], a[7]);
    }
}

extern "C" void kernel_launch(void* const* d_in, const int* in_sizes, int n_in,
                              void* d_out, int out_size, void* d_ws, size_t ws_size,
                              hipStream_t stream) {
    const int*   edge_row  = (const int*)d_in[0];
    const int*   edge_col  = (const int*)d_in[1];
    const float* edge_vals = (const float*)d_in[2];
    const float* x         = (const float*)d_in[3];
    const float* sp        = (const float*)d_in[4];
    const float* lw        = (const float*)d_in[5];
    float* out = (float*)d_out;

    const int E_ = in_sizes[0];
    const int N_ = in_sizes[3] / D;

    // Workspace: row_ptr | wwB (fp16, frag layout) | bufA (N*D f16) | bufB
    char* ws = (char*)d_ws;
    int* row_ptr = (int*)ws;
    size_t off = (((size_t)(N_ + 1) * sizeof(int)) + 255) & ~(size_t)255;
    _Float16* wwB = (_Float16*)(ws + off);
    off += (size_t)L * 4 * D * 32 * sizeof(_Float16);
    off = (off + 255) & ~(size_t)255;
    _Float16* bufA = (_Float16*)(ws + off);
    off += (size_t)N_ * D * sizeof(_Float16);
    _Float16* bufB = (_Float16*)(ws + off);

    build_row_ptr<<<(N_ + 1 + 255) / 256, 256, 0, stream>>>(edge_row, row_ptr, N_, E_);
    build_ww<<<(L * D * D + 255) / 256, 256, 0, stream>>>(sp, lw, wwB);
    cast_f16<<<(N_ * D / 4 + 255) / 256, 256, 0, stream>>>(x, bufA, N_ * D / 4);

    const int gblk = (N_ + 63) / 64;
    const int sblk = (N_ + 15) / 16;
    const int WWL = 4 * D * 32;   // per-layer wwB stride

    // L0: Y1 = A*W0 (in-place A); h1 = relu(adj*Y1) -> B (f16)
    gemm_xw<<<gblk, 256, 0, stream>>>(bufA, wwB,            bufA, N_);
    spmm<true,  true ><<<sblk, 256, 0, stream>>>(bufA, row_ptr, edge_col, edge_vals, bufB, N_);
    // L1: Y2 = B*W1 (in-place B); h2 = relu(adj*Y2) -> A (f16)
    gemm_xw<<<gblk, 256, 0, stream>>>(bufB, wwB + WWL,      bufB, N_);
    spmm<true,  true ><<<sblk, 256, 0, stream>>>(bufB, row_ptr, edge_col, edge_vals, bufA, N_);
    // L2: Y3 = A*W2 (in-place A); out = adj*Y3 -> d_out (fp32, no relu)
    gemm_xw<<<gblk, 256, 0, stream>>>(bufA, wwB + 2 * WWL,  bufA, N_);
    spmm<false, false><<<sblk, 256, 0, stream>>>(bufA, row_ptr, edge_col, edge_vals, out,  N_);
}

// Round 8
// 339.234 us; speedup vs baseline: 8.8055x; 1.0867x over previous
//
#include <hip/hip_runtime.h>
#include <cstdint>

#define D 128
#define P 8
#define L 3

typedef __attribute__((ext_vector_type(8))) _Float16 f16x8;
typedef __attribute__((ext_vector_type(4))) float    f32x4;

// row_ptr[r] = lower_bound(edge_row, r); edge_row is sorted.
__global__ void build_row_ptr(const int* __restrict__ er, int* __restrict__ rp, int n, int e) {
    int r = blockIdx.x * blockDim.x + threadIdx.x;
    if (r > n) return;
    int lo = 0, hi = e;
    while (lo < hi) {
        int mid = (lo + hi) >> 1;
        if (er[mid] < r) lo = mid + 1; else hi = mid;
    }
    rp[r] = lo;
}

// ww = softmax-contracted weights, fp16, MFMA B-fragment layout:
// wwB[l][kt][o][k']  (i = kt*32 + k'); b-frag load is 16B contiguous.
__global__ void build_ww(const float* __restrict__ sp, const float* __restrict__ lw,
                         _Float16* __restrict__ wwB) {
    int idx = blockIdx.x * blockDim.x + threadIdx.x;
    if (idx >= L * D * D) return;
    int l = idx / (D * D);
    int rem = idx - l * D * D;
    int o = rem / D;
    int i = rem - o * D;
    float wv[P];
    float m = -1e30f;
#pragma unroll
    for (int p = 0; p < P; p++) { wv[p] = lw[l * P + p]; m = fmaxf(m, wv[p]); }
    float s = 0.f;
#pragma unroll
    for (int p = 0; p < P; p++) { wv[p] = __expf(wv[p] - m); s += wv[p]; }
    float inv = 1.0f / s;
    const float* spp = sp + ((size_t)(l * D + o) * D + i) * P;
    float acc = 0.f;
#pragma unroll
    for (int p = 0; p < P; p++) acc += spp[p] * wv[p];
    int kt = i >> 5, kp = i & 31;
    wwB[(((l * 4 + kt) * D + o) << 5) + kp] = (_Float16)(acc * inv);
}

// MFMA phase: s_h (64x128 f16 tile, +8 pad) times wwB_l -> y rows row0..row0+63.
static __device__ __forceinline__ void mfma_store(const _Float16 (*s_h)[136],
                                                  const _Float16* __restrict__ wwB_l,
                                                  _Float16* __restrict__ y,
                                                  int row0, int n, int tid) {
    const int w = tid >> 6, lane = tid & 63;
    const int quad = lane >> 4, l16 = lane & 15;
    f32x4 acc[8] = {};
    const int arow = w * 16 + l16;
#pragma unroll
    for (int kt = 0; kt < 4; kt++) {
        f16x8 af = *(const f16x8*)&s_h[arow][kt * 32 + quad * 8];
#pragma unroll
        for (int ct = 0; ct < 8; ct++) {
            f16x8 bf = *(const f16x8*)&wwB_l[((kt * D + ct * 16 + l16) << 5) + quad * 8];
            acc[ct] = __builtin_amdgcn_mfma_f32_16x16x32_f16(af, bf, acc[ct], 0, 0, 0);
        }
    }
    // C/D layout: col = lane&15, row = quad*4 + reg (m89-verified)
#pragma unroll
    for (int ct = 0; ct < 8; ct++) {
#pragma unroll
        for (int rg = 0; rg < 4; rg++) {
            int row = row0 + w * 16 + quad * 4 + rg;
            if (row < n) y[row * D + ct * 16 + l16] = (_Float16)acc[ct][rg];
        }
    }
}

// Y1 = cast_f16(x) * W0   (x fp32 read directly; cast fused)
__global__ __launch_bounds__(256, 6)
void gemm_x32(const float* __restrict__ x, const _Float16* __restrict__ wwB_l,
              _Float16* __restrict__ y, int n) {
    __shared__ _Float16 s_h[64][136];
    const int tid = threadIdx.x;
    const int row0 = blockIdx.x * 64;
    const int c8 = (tid & 15) * 8;
    for (int r = tid >> 4; r < 64; r += 16) {
        int row = row0 + r;
        float4 v0 = {}, v1 = {};
        if (row < n) {
            v0 = *(const float4*)&x[row * D + c8];
            v1 = *(const float4*)&x[row * D + c8 + 4];
        }
        f16x8 h;
        h[0] = (_Float16)v0.x; h[1] = (_Float16)v0.y;
        h[2] = (_Float16)v0.z; h[3] = (_Float16)v0.w;
        h[4] = (_Float16)v1.x; h[5] = (_Float16)v1.y;
        h[6] = (_Float16)v1.z; h[7] = (_Float16)v1.w;
        *(f16x8*)&s_h[r][c8] = h;
    }
    __syncthreads();
    mfma_store(s_h, wwB_l, y, row0, n, tid);
}

// gather-accumulate core: a[8] += vals[e] * yprev[col[e]][c8..c8+7], batched
static __device__ __forceinline__ void gather_row(float (&a)[8],
                                                  const _Float16* __restrict__ y,
                                                  const int* __restrict__ col,
                                                  const float* __restrict__ vals,
                                                  int e, int e1, int c8) {
    union U8 { uint4 u; _Float16 h[8]; };
    for (; e + 8 <= e1; e += 8) {
        int c[8]; float v[8]; U8 g[8];
#pragma unroll
        for (int j = 0; j < 8; j++) { c[j] = col[e + j]; v[j] = vals[e + j]; }
#pragma unroll
        for (int j = 0; j < 8; j++) g[j].u = *(const uint4*)&y[c[j] * D + c8];
#pragma unroll
        for (int j = 0; j < 8; j++)
#pragma unroll
            for (int k = 0; k < 8; k++) a[k] += v[j] * (float)g[j].h[k];
    }
    for (; e + 4 <= e1; e += 4) {
        int c[4]; float v[4]; U8 g[4];
#pragma unroll
        for (int j = 0; j < 4; j++) { c[j] = col[e + j]; v[j] = vals[e + j]; }
#pragma unroll
        for (int j = 0; j < 4; j++) g[j].u = *(const uint4*)&y[c[j] * D + c8];
#pragma unroll
        for (int j = 0; j < 4; j++)
#pragma unroll
            for (int k = 0; k < 8; k++) a[k] += v[j] * (float)g[j].h[k];
    }
    for (; e < e1; e++) {
        U8 g; g.u = *(const uint4*)&y[col[e] * D + c8];
        float v = vals[e];
#pragma unroll
        for (int k = 0; k < 8; k++) a[k] += v * (float)g.h[k];
    }
}

// Fused layer: Y_next = relu(adj * Y_prev) * W.  H lives only in LDS.
__global__ __launch_bounds__(256, 6)
void fused_layer(const _Float16* __restrict__ yprev, const int* __restrict__ rp,
                 const int* __restrict__ col, const float* __restrict__ vals,
                 const _Float16* __restrict__ wwB_l, _Float16* __restrict__ ynext, int n) {
    __shared__ _Float16 s_h[64][136];
    const int tid = threadIdx.x;
    const int row0 = blockIdx.x * 64;
    const int sg = tid >> 4;          // 0..15
    const int c8 = (tid & 15) * 8;
    for (int rr = sg; rr < 64; rr += 16) {
        int r = row0 + rr;
        float a[8] = {0.f, 0.f, 0.f, 0.f, 0.f, 0.f, 0.f, 0.f};
        if (r < n) gather_row(a, yprev, col, vals, rp[r], rp[r + 1], c8);
        f16x8 o;
#pragma unroll
        for (int k = 0; k < 8; k++) o[k] = (_Float16)fmaxf(a[k], 0.f);
        *(f16x8*)&s_h[rr][c8] = o;
    }
    __syncthreads();
    mfma_store(s_h, wwB_l, ynext, row0, n, tid);
}

// Final: out = adj * Y3, fp32 out. No LDS -> 8 blocks/CU.
__global__ __launch_bounds__(256, 8)
void spmm_f32(const _Float16* __restrict__ y, const int* __restrict__ rp,
              const int* __restrict__ col, const float* __restrict__ vals,
              float* __restrict__ out, int n) {
    const int tid = threadIdx.x;
    const int r = blockIdx.x * 16 + (tid >> 4);
    const int c8 = (tid & 15) * 8;
    if (r >= n) return;
    float a[8] = {0.f, 0.f, 0.f, 0.f, 0.f, 0.f, 0.f, 0.f};
    gather_row(a, y, col, vals, rp[r], rp[r + 1], c8);
    *(float4*)&out[r * D + c8]     = make_float4(a[0], a[1], a[2], a[3]);
    *(float4*)&out[r * D + c8 + 4] = make_float4(a[4], a[5], a[6], a[7]);
}

extern "C" void kernel_launch(void* const* d_in, const int* in_sizes, int n_in,
                              void* d_out, int out_size, void* d_ws, size_t ws_size,
                              hipStream_t stream) {
    const int*   edge_row  = (const int*)d_in[0];
    const int*   edge_col  = (const int*)d_in[1];
    const float* edge_vals = (const float*)d_in[2];
    const float* x         = (const float*)d_in[3];
    const float* sp        = (const float*)d_in[4];
    const float* lw        = (const float*)d_in[5];
    float* out = (float*)d_out;

    const int E_ = in_sizes[0];
    const int N_ = in_sizes[3] / D;

    // Workspace: row_ptr | wwB (fp16 frag layout) | bufA (N*D f16) | bufB
    char* ws = (char*)d_ws;
    int* row_ptr = (int*)ws;
    size_t off = (((size_t)(N_ + 1) * sizeof(int)) + 255) & ~(size_t)255;
    _Float16* wwB = (_Float16*)(ws + off);
    off += (size_t)L * 4 * D * 32 * sizeof(_Float16);
    off = (off + 255) & ~(size_t)255;
    _Float16* bufA = (_Float16*)(ws + off);
    off += (size_t)N_ * D * sizeof(_Float16);
    _Float16* bufB = (_Float16*)(ws + off);

    build_row_ptr<<<(N_ + 1 + 255) / 256, 256, 0, stream>>>(edge_row, row_ptr, N_, E_);
    build_ww<<<(L * D * D + 255) / 256, 256, 0, stream>>>(sp, lw, wwB);

    const int gblk = (N_ + 63) / 64;
    const int sblk = (N_ + 15) / 16;
    const int WWL = 4 * D * 32;   // per-layer wwB stride

    // Y1 = x*W0 ; Y2 = relu(adj*Y1)*W1 ; Y3 = relu(adj*Y2)*W2 ; out = adj*Y3
    gemm_x32<<<gblk, 256, 0, stream>>>(x, wwB, bufA, N_);
    fused_layer<<<gblk, 256, 0, stream>>>(bufA, row_ptr, edge_col, edge_vals,
                                          wwB + WWL,     bufB, N_);
    fused_layer<<<gblk, 256, 0, stream>>>(bufB, row_ptr, edge_col, edge_vals,
                                          wwB + 2 * WWL, bufA, N_);
    spmm_f32<<<sblk, 256, 0, stream>>>(bufA, row_ptr, edge_col, edge_vals, out, N_);
}

// Round 9
// 316.839 us; speedup vs baseline: 9.4279x; 1.0707x over previous
//
#include <hip/hip_runtime.h>
#include <cstdint>

#define D 128
#define P 8
#define L 3

typedef __attribute__((ext_vector_type(8))) _Float16 f16x8;
typedef __attribute__((ext_vector_type(4))) float    f32x4;

// row_ptr[r] = lower_bound(edge_row, r); edge_row is sorted.
__global__ void build_row_ptr(const int* __restrict__ er, int* __restrict__ rp, int n, int e) {
    int r = blockIdx.x * blockDim.x + threadIdx.x;
    if (r > n) return;
    int lo = 0, hi = e;
    while (lo < hi) {
        int mid = (lo + hi) >> 1;
        if (er[mid] < r) lo = mid + 1; else hi = mid;
    }
    rp[r] = lo;
}

// ww = softmax-contracted weights, fp16, MFMA B-fragment layout:
// wwB[l][kt][o][k']  (i = kt*32 + k'); b-frag load is 16B contiguous.
__global__ void build_ww(const float* __restrict__ sp, const float* __restrict__ lw,
                         _Float16* __restrict__ wwB) {
    int idx = blockIdx.x * blockDim.x + threadIdx.x;
    if (idx >= L * D * D) return;
    int l = idx / (D * D);
    int rem = idx - l * D * D;
    int o = rem / D;
    int i = rem - o * D;
    float wv[P];
    float m = -1e30f;
#pragma unroll
    for (int p = 0; p < P; p++) { wv[p] = lw[l * P + p]; m = fmaxf(m, wv[p]); }
    float s = 0.f;
#pragma unroll
    for (int p = 0; p < P; p++) { wv[p] = __expf(wv[p] - m); s += wv[p]; }
    float inv = 1.0f / s;
    const float* spp = sp + ((size_t)(l * D + o) * D + i) * P;
    float acc = 0.f;
#pragma unroll
    for (int p = 0; p < P; p++) acc += spp[p] * wv[p];
    int kt = i >> 5, kp = i & 31;
    wwB[(((l * 4 + kt) * D + o) << 5) + kp] = (_Float16)(acc * inv);
}

// MFMA on a 16x128 staged tile: 8 output col-tiles split 2-per-wave.
// All 4 waves read the same 16 rows (LDS broadcast).
static __device__ __forceinline__ void mfma_store16(const _Float16 (*s_h)[136],
                                                    const _Float16* __restrict__ wwB_l,
                                                    _Float16* __restrict__ y,
                                                    int row0, int n, int tid) {
    const int w = tid >> 6, lane = tid & 63;
    const int quad = lane >> 4, l16 = lane & 15;
    f32x4 acc[2] = {};
#pragma unroll
    for (int kt = 0; kt < 4; kt++) {
        f16x8 af = *(const f16x8*)&s_h[l16][kt * 32 + quad * 8];
#pragma unroll
        for (int c = 0; c < 2; c++) {
            const int ct = w * 2 + c;
            f16x8 bf = *(const f16x8*)&wwB_l[((kt * D + ct * 16 + l16) << 5) + quad * 8];
            acc[c] = __builtin_amdgcn_mfma_f32_16x16x32_f16(af, bf, acc[c], 0, 0, 0);
        }
    }
    // C/D layout: col = lane&15, row = quad*4 + reg (m89-verified)
#pragma unroll
    for (int c = 0; c < 2; c++) {
        const int ct = w * 2 + c;
#pragma unroll
        for (int rg = 0; rg < 4; rg++) {
            int row = row0 + quad * 4 + rg;
            if (row < n) y[row * D + ct * 16 + l16] = (_Float16)acc[c][rg];
        }
    }
}

// Y1 = cast_f16(x) * W0   (x fp32 read directly; cast fused). 16-row tiles.
__global__ __launch_bounds__(256, 8)
void gemm_x32(const float* __restrict__ x, const _Float16* __restrict__ wwB_l,
              _Float16* __restrict__ y, int n) {
    __shared__ _Float16 s_h[16][136];
    const int tid = threadIdx.x;
    const int row0 = blockIdx.x * 16;
    const int c8 = (tid & 15) * 8;
    {
        int r = tid >> 4;              // 0..15, one row per subgroup
        int row = row0 + r;
        float4 v0 = {}, v1 = {};
        if (row < n) {
            v0 = *(const float4*)&x[row * D + c8];
            v1 = *(const float4*)&x[row * D + c8 + 4];
        }
        f16x8 h;
        h[0] = (_Float16)v0.x; h[1] = (_Float16)v0.y;
        h[2] = (_Float16)v0.z; h[3] = (_Float16)v0.w;
        h[4] = (_Float16)v1.x; h[5] = (_Float16)v1.y;
        h[6] = (_Float16)v1.z; h[7] = (_Float16)v1.w;
        *(f16x8*)&s_h[r][c8] = h;
    }
    __syncthreads();
    mfma_store16(s_h, wwB_l, y, row0, n, tid);
}

// gather-accumulate core: a[8] += vals[e] * yprev[col[e]][c8..c8+7], batched
static __device__ __forceinline__ void gather_row(float (&a)[8],
                                                  const _Float16* __restrict__ y,
                                                  const int* __restrict__ col,
                                                  const float* __restrict__ vals,
                                                  int e, int e1, int c8) {
    union U8 { uint4 u; _Float16 h[8]; };
    for (; e + 8 <= e1; e += 8) {
        int c[8]; float v[8]; U8 g[8];
#pragma unroll
        for (int j = 0; j < 8; j++) { c[j] = col[e + j]; v[j] = vals[e + j]; }
#pragma unroll
        for (int j = 0; j < 8; j++) g[j].u = *(const uint4*)&y[c[j] * D + c8];
#pragma unroll
        for (int j = 0; j < 8; j++)
#pragma unroll
            for (int k = 0; k < 8; k++) a[k] += v[j] * (float)g[j].h[k];
    }
    for (; e + 4 <= e1; e += 4) {
        int c[4]; float v[4]; U8 g[4];
#pragma unroll
        for (int j = 0; j < 4; j++) { c[j] = col[e + j]; v[j] = vals[e + j]; }
#pragma unroll
        for (int j = 0; j < 4; j++) g[j].u = *(const uint4*)&y[c[j] * D + c8];
#pragma unroll
        for (int j = 0; j < 4; j++)
#pragma unroll
            for (int k = 0; k < 8; k++) a[k] += v[j] * (float)g[j].h[k];
    }
    for (; e < e1; e++) {
        U8 g; g.u = *(const uint4*)&y[col[e] * D + c8];
        float v = vals[e];
#pragma unroll
        for (int k = 0; k < 8; k++) a[k] += v * (float)g.h[k];
    }
}

// Fused layer: Y_next = relu(adj * Y_prev) * W.  16-row tiles, H only in LDS.
__global__ __launch_bounds__(256, 8)
void fused_layer(const _Float16* __restrict__ yprev, const int* __restrict__ rp,
                 const int* __restrict__ col, const float* __restrict__ vals,
                 const _Float16* __restrict__ wwB_l, _Float16* __restrict__ ynext, int n) {
    __shared__ _Float16 s_h[16][136];
    const int tid = threadIdx.x;
    const int row0 = blockIdx.x * 16;
    const int sg = tid >> 4;          // 0..15, one row per subgroup
    const int c8 = (tid & 15) * 8;
    {
        int r = row0 + sg;
        float a[8] = {0.f, 0.f, 0.f, 0.f, 0.f, 0.f, 0.f, 0.f};
        if (r < n) gather_row(a, yprev, col, vals, rp[r], rp[r + 1], c8);
        f16x8 o;
#pragma unroll
        for (int k = 0; k < 8; k++) o[k] = (_Float16)fmaxf(a[k], 0.f);
        *(f16x8*)&s_h[sg][c8] = o;
    }
    __syncthreads();
    mfma_store16(s_h, wwB_l, ynext, row0, n, tid);
}

// Final: out = adj * Y3, fp32 out. No LDS.
__global__ __launch_bounds__(256, 8)
void spmm_f32(const _Float16* __restrict__ y, const int* __restrict__ rp,
              const int* __restrict__ col, const float* __restrict__ vals,
              float* __restrict__ out, int n) {
    const int tid = threadIdx.x;
    const int r = blockIdx.x * 16 + (tid >> 4);
    const int c8 = (tid & 15) * 8;
    if (r >= n) return;
    float a[8] = {0.f, 0.f, 0.f, 0.f, 0.f, 0.f, 0.f, 0.f};
    gather_row(a, y, col, vals, rp[r], rp[r + 1], c8);
    *(float4*)&out[r * D + c8]     = make_float4(a[0], a[1], a[2], a[3]);
    *(float4*)&out[r * D + c8 + 4] = make_float4(a[4], a[5], a[6], a[7]);
}

extern "C" void kernel_launch(void* const* d_in, const int* in_sizes, int n_in,
                              void* d_out, int out_size, void* d_ws, size_t ws_size,
                              hipStream_t stream) {
    const int*   edge_row  = (const int*)d_in[0];
    const int*   edge_col  = (const int*)d_in[1];
    const float* edge_vals = (const float*)d_in[2];
    const float* x         = (const float*)d_in[3];
    const float* sp        = (const float*)d_in[4];
    const float* lw        = (const float*)d_in[5];
    float* out = (float*)d_out;

    const int E_ = in_sizes[0];
    const int N_ = in_sizes[3] / D;

    // Workspace: row_ptr | wwB (fp16 frag layout) | bufA (N*D f16) | bufB
    char* ws = (char*)d_ws;
    int* row_ptr = (int*)ws;
    size_t off = (((size_t)(N_ + 1) * sizeof(int)) + 255) & ~(size_t)255;
    _Float16* wwB = (_Float16*)(ws + off);
    off += (size_t)L * 4 * D * 32 * sizeof(_Float16);
    off = (off + 255) & ~(size_t)255;
    _Float16* bufA = (_Float16*)(ws + off);
    off += (size_t)N_ * D * sizeof(_Float16);
    _Float16* bufB = (_Float16*)(ws + off);

    build_row_ptr<<<(N_ + 1 + 255) / 256, 256, 0, stream>>>(edge_row, row_ptr, N_, E_);
    build_ww<<<(L * D * D + 255) / 256, 256, 0, stream>>>(sp, lw, wwB);

    const int sblk = (N_ + 15) / 16;
    const int WWL = 4 * D * 32;   // per-layer wwB stride

    // Y1 = x*W0 ; Y2 = relu(adj*Y1)*W1 ; Y3 = relu(adj*Y2)*W2 ; out = adj*Y3
    gemm_x32<<<sblk, 256, 0, stream>>>(x, wwB, bufA, N_);
    fused_layer<<<sblk, 256, 0, stream>>>(bufA, row_ptr, edge_col, edge_vals,
                                          wwB + WWL,     bufB, N_);
    fused_layer<<<sblk, 256, 0, stream>>>(bufB, row_ptr, edge_col, edge_vals,
                                          wwB + 2 * WWL, bufA, N_);
    spmm_f32<<<sblk, 256, 0, stream>>>(bufA, row_ptr, edge_col, edge_vals, out, N_);
}